// Round 10
// baseline (385.010 us; speedup 1.0000x reference)
//
#include <hip/hip_runtime.h>

typedef unsigned short u16;
typedef short short8 __attribute__((ext_vector_type(8)));
typedef float f32x4 __attribute__((ext_vector_type(4)));

// ---------- helpers ----------
__device__ __forceinline__ u16 f2b(float x){
  union{float f; unsigned u;} v; v.f = x;
  unsigned r = (v.u + 0x7FFFu + ((v.u >> 16) & 1u)) >> 16;
  return (u16)r;
}
__device__ __forceinline__ u16 f2h(float x){
  union{_Float16 h; u16 u;} c; c.h = (_Float16)x; return c.u;
}
__device__ __forceinline__ float b2f(u16 h){
  union{unsigned u; float f;} v; v.u = ((unsigned)h) << 16; return v.f;
}
__device__ __forceinline__ float sigm(float x){ return 1.0f/(1.0f + __expf(-x)); }
__device__ __forceinline__ float tanh_f(float x){ return 1.0f - 2.0f/(1.0f + __expf(2.0f*x)); }

// ---------- prep: xe gather->bf16, Wcomb, bias, Whh unit-major f16 repack, W1 repack, hbt pad ----------
__global__ void prep_kernel(const int* __restrict__ x, const float* __restrict__ emb,
   const float* __restrict__ Wih_f, const float* __restrict__ Whh_f,
   const float* __restrict__ bih_f, const float* __restrict__ bhh_f,
   const float* __restrict__ Wih_b, const float* __restrict__ Whh_b,
   const float* __restrict__ bih_b, const float* __restrict__ bhh_b,
   const float* __restrict__ W1,
   u16* __restrict__ xe, u16* __restrict__ wc, float* __restrict__ biasC,
   u16* __restrict__ whhU, u16* __restrict__ w1b, u16* __restrict__ hbt)
{
  int id = blockIdx.x*256 + threadIdx.x;
  const int N0 = 32768*128;   // xe  [p][k]
  const int N1 = 832*128;     // wc  [n][k]
  const int N2 = 800;         // biasC
  const int N3 = 106496;      // whhU [d][u(128)][g(4)][k(104)] f16, zero-padded
  const int N4 = 672*320;     // w1b  (id = k*320+n)
  const int N5 = 32768*24;    // hbt pad cols 200..223
  if (id < N0){
    int p = id >> 7, k = id & 127;
    float v = 0.f;
    if (k < 100) v = emb[x[p]*100 + k];
    xe[id] = f2b(v);
    return;
  }
  id -= N0;
  if (id < N1){
    int n = id >> 7, k = id & 127;
    float v = 0.f;
    if (k < 100){
      if (n < 400) v = Wih_f[n*100+k];
      else if (n < 800) v = Wih_b[(n-400)*100+k];
    }
    wc[id] = f2b(v);
    return;
  }
  id -= N1;
  if (id < N2){
    biasC[id] = (id < 400) ? (bih_f[id]+bhh_f[id]) : (bih_b[id-400]+bhh_b[id-400]);
    return;
  }
  id -= N2;
  if (id < N3){
    int d = id / 53248; int rem = id - d*53248;
    int u = rem / 416;  int r2 = rem - u*416;
    int g = r2 / 104;   int k = r2 - g*104;
    float v = 0.f;
    if (u < 100 && k < 100){
      const float* W = d ? Whh_b : Whh_f;
      v = W[(g*100 + u)*100 + k];
    }
    whhU[id] = f2h(v);
    return;
  }
  id -= N3;
  if (id < N4){
    int k = id / 320; int n = id - k*320;
    int seg = k / 224; int wwk = k - seg*224;
    float v = 0.f;
    if (n < 300 && wwk < 200) v = W1[(seg*200 + wwk)*300 + n];
    w1b[n*672 + k] = f2b(v);
    return;
  }
  id -= N4;
  if (id < N5){
    int p = id / 24; int k = id - p*24;
    hbt[p*224 + 200 + k] = 0;
  }
}

// ---------- GEMM1: inp[d][b][t][u*4+g] = xe @ Wcomb^T + bias, bf16 MFMA ----------
__global__ __launch_bounds__(256) void gemm1_kernel(const u16* __restrict__ xe,
    const u16* __restrict__ wc, const float* __restrict__ biasC, u16* __restrict__ inp)
{
  __shared__ __align__(16) u16 As[64*136];
  __shared__ __align__(16) u16 Bs[64*136];
  const int m0 = blockIdx.x*64, n0 = blockIdx.y*64;
  const int tid = threadIdx.x;
  #pragma unroll
  for (int i=0;i<4;i++){
    int f = i*256 + tid;
    int row = f >> 4, c8 = f & 15;
    *(uint4*)&As[row*136 + c8*8] = *(const uint4*)&xe[(m0+row)*128 + c8*8];
    *(uint4*)&Bs[row*136 + c8*8] = *(const uint4*)&wc[(n0+row)*128 + c8*8];
  }
  __syncthreads();
  const int w = tid >> 6, lane = tid & 63, col = lane & 15, quad = lane >> 4;
  f32x4 acc[4];
  #pragma unroll
  for (int nt=0;nt<4;nt++) acc[nt] = (f32x4){0.f,0.f,0.f,0.f};
  #pragma unroll
  for (int kc=0;kc<4;kc++){
    short8 af = *(const short8*)&As[(w*16+col)*136 + kc*32 + quad*8];
    #pragma unroll
    for (int nt=0;nt<4;nt++){
      short8 bfrag = *(const short8*)&Bs[(nt*16+col)*136 + kc*32 + quad*8];
      acc[nt] = __builtin_amdgcn_mfma_f32_16x16x32_bf16(af, bfrag, acc[nt], 0, 0, 0);
    }
  }
  #pragma unroll
  for (int nt=0;nt<4;nt++){
    int n = n0 + nt*16 + col;
    if (n < 800){
      float bs = biasC[n];
      int dir = (n >= 400) ? 1 : 0;
      int j = n - dir*400;
      int gg = j / 100, uu = j - gg*100;
      int pj = uu*4 + gg;
      #pragma unroll
      for (int r=0;r<4;r++){
        int m = m0 + w*16 + quad*4 + r;
        inp[(dir*32768 + m)*400 + pj] = f2b(acc[nt][r] + bs);
      }
    }
  }
}

// ---------- LSTM: unit-major, 2 waves/chain, weights fully register-resident ----------
// r9 calibration: VALUBusy 69.6% == 1-(1-p)^4 at p=26%/SIMD -> the 14-wave
// barrier-lockstep regime wastes 74% of issue slots. This design: 128 thr/chain,
// lane = unit u; ALL 4 gate rows (104-k f16) in regs v32-v239 (208 dwords).
// Zero cross-lane compute (no swizzle/DPP/cndmask, 1 activation per unit);
// 512 blocks x 2 waves = 4 waves/CU, 1/SIMD, 2 independent blocks/CU.
// Per step: 13 broadcast ds_read_b128 (2-buffer pipeline), 208 v_dot2
// (4 interleaved acc chains), act chain (r8 constants), 1 ds_write_b16 + 1
// global_store_short (exec-masked u<100), one 2-wave barrier.
#define DOT4(W0,W1,W2,W3,H) \
  "v_dot2_f32_f16 v16, v" #W0 ", v" #H ", v16\n\t" \
  "v_dot2_f32_f16 v17, v" #W1 ", v" #H ", v17\n\t" \
  "v_dot2_f32_f16 v18, v" #W2 ", v" #H ", v18\n\t" \
  "v_dot2_f32_f16 v19, v" #W3 ", v" #H ", v19\n\t"

__global__ __launch_bounds__(128, 1) void lstm_kernel(const u16* __restrict__ inp,
    const u16* __restrict__ whhU, u16* __restrict__ hbt)
{
  __shared__ __align__(512) u16 hs2[256];   // 2 bufs x 128 f16 (256B each), XOR 0x100
  const int cid = blockIdx.x;
  const int b = cid & 255, dir = cid >> 8;
  const int tid = threadIdx.x;
  ((float*)hs2)[tid] = 0.f;                 // 128 threads zero 512B
  __syncthreads();
  unsigned long long se = __ballot(tid < 100);   // per-wave store mask
  const int sw  = tid >> 6;                      // wave id (uniform)
  const int t0  = dir ? 127 : 0;
  const int dIb = dir ? -800 : 800;              // inp byte stride per step
  const int dHb = dir ? -448 : 448;              // hbt byte stride per step
  const int swb = dir*106496;                    // whhU dir base (bytes)
  const unsigned sio = (unsigned)((dir*32768 + b*128 + t0)*400) * 2u;
  const unsigned sho = (unsigned)((b*128 + t0)*224 + dir*100) * 2u;
  const unsigned sra = (unsigned)(size_t)&hs2[0];
  const unsigned sha = sra + 256u;
  asm volatile(
    // ---- prologue: per-lane addresses; weights (52 dwordx4) + inp prefetch ----
    "v_mbcnt_lo_u32_b32 v22, -1, 0\n\t"
    "v_mbcnt_hi_u32_b32 v22, -1, v22\n\t"        // lane
    "v_lshl_add_u32 v22, %[sw], 6, v22\n\t"      // u = tid
    "v_mul_u32_u24 v27, 832, v22\n\t"            // u*832 (weight bytes/unit)
    "v_add_u32 v27, %[swb], v27\n\t"             // weight base
    "v_lshl_add_u32 v26, v22, 3, %[sio]\n\t"     // inp addr (u*8, dwordx2)
    "v_lshl_add_u32 v25, v22, 1, %[sho]\n\t"     // hbt addr
    "v_lshl_add_u32 v24, v22, 1, %[sha]\n\t"     // h write addr (buf1)
    "v_mov_b32 v23, %[sra]\n\t"                  // h read base (buf0, uniform)
    "v_mov_b32 v30, 0\n\t"                       // c-state
    "s_mov_b32 s20, 128\n\t"
    "global_load_dwordx2 v[20:21], v26, %[ib]\n\t"
    "v_add_u32 v26, %[dis], v26\n\t"
    // gate 0 rows (k 0..103), mem off 0..192
    "global_load_dwordx4 v[32:35], v27, %[wb]\n\t"
    "global_load_dwordx4 v[36:39], v27, %[wb] offset:16\n\t"
    "global_load_dwordx4 v[40:43], v27, %[wb] offset:32\n\t"
    "global_load_dwordx4 v[44:47], v27, %[wb] offset:48\n\t"
    "global_load_dwordx4 v[48:51], v27, %[wb] offset:64\n\t"
    "global_load_dwordx4 v[52:55], v27, %[wb] offset:80\n\t"
    "global_load_dwordx4 v[56:59], v27, %[wb] offset:96\n\t"
    "global_load_dwordx4 v[60:63], v27, %[wb] offset:112\n\t"
    "global_load_dwordx4 v[64:67], v27, %[wb] offset:128\n\t"
    "global_load_dwordx4 v[68:71], v27, %[wb] offset:144\n\t"
    "global_load_dwordx4 v[72:75], v27, %[wb] offset:160\n\t"
    "global_load_dwordx4 v[76:79], v27, %[wb] offset:176\n\t"
    "global_load_dwordx4 v[80:83], v27, %[wb] offset:192\n\t"
    // gate 1, mem off 208..400
    "global_load_dwordx4 v[84:87],  v27, %[wb] offset:208\n\t"
    "global_load_dwordx4 v[88:91],  v27, %[wb] offset:224\n\t"
    "global_load_dwordx4 v[92:95],  v27, %[wb] offset:240\n\t"
    "global_load_dwordx4 v[96:99],  v27, %[wb] offset:256\n\t"
    "global_load_dwordx4 v[100:103], v27, %[wb] offset:272\n\t"
    "global_load_dwordx4 v[104:107], v27, %[wb] offset:288\n\t"
    "global_load_dwordx4 v[108:111], v27, %[wb] offset:304\n\t"
    "global_load_dwordx4 v[112:115], v27, %[wb] offset:320\n\t"
    "global_load_dwordx4 v[116:119], v27, %[wb] offset:336\n\t"
    "global_load_dwordx4 v[120:123], v27, %[wb] offset:352\n\t"
    "global_load_dwordx4 v[124:127], v27, %[wb] offset:368\n\t"
    "global_load_dwordx4 v[128:131], v27, %[wb] offset:384\n\t"
    "global_load_dwordx4 v[132:135], v27, %[wb] offset:400\n\t"
    // gate 2, mem off 416..608
    "global_load_dwordx4 v[136:139], v27, %[wb] offset:416\n\t"
    "global_load_dwordx4 v[140:143], v27, %[wb] offset:432\n\t"
    "global_load_dwordx4 v[144:147], v27, %[wb] offset:448\n\t"
    "global_load_dwordx4 v[148:151], v27, %[wb] offset:464\n\t"
    "global_load_dwordx4 v[152:155], v27, %[wb] offset:480\n\t"
    "global_load_dwordx4 v[156:159], v27, %[wb] offset:496\n\t"
    "global_load_dwordx4 v[160:163], v27, %[wb] offset:512\n\t"
    "global_load_dwordx4 v[164:167], v27, %[wb] offset:528\n\t"
    "global_load_dwordx4 v[168:171], v27, %[wb] offset:544\n\t"
    "global_load_dwordx4 v[172:175], v27, %[wb] offset:560\n\t"
    "global_load_dwordx4 v[176:179], v27, %[wb] offset:576\n\t"
    "global_load_dwordx4 v[180:183], v27, %[wb] offset:592\n\t"
    "global_load_dwordx4 v[184:187], v27, %[wb] offset:608\n\t"
    // gate 3, mem off 624..816
    "global_load_dwordx4 v[188:191], v27, %[wb] offset:624\n\t"
    "global_load_dwordx4 v[192:195], v27, %[wb] offset:640\n\t"
    "global_load_dwordx4 v[196:199], v27, %[wb] offset:656\n\t"
    "global_load_dwordx4 v[200:203], v27, %[wb] offset:672\n\t"
    "global_load_dwordx4 v[204:207], v27, %[wb] offset:688\n\t"
    "global_load_dwordx4 v[208:211], v27, %[wb] offset:704\n\t"
    "global_load_dwordx4 v[212:215], v27, %[wb] offset:720\n\t"
    "global_load_dwordx4 v[216:219], v27, %[wb] offset:736\n\t"
    "global_load_dwordx4 v[220:223], v27, %[wb] offset:752\n\t"
    "global_load_dwordx4 v[224:227], v27, %[wb] offset:768\n\t"
    "global_load_dwordx4 v[228:231], v27, %[wb] offset:784\n\t"
    "global_load_dwordx4 v[232:235], v27, %[wb] offset:800\n\t"
    "global_load_dwordx4 v[236:239], v27, %[wb] offset:816\n\t"
    "LSTM_T%=:\n\t"
    // wait weights (first iter) + inp prefetch; init accs from preacts; reissue
    "s_waitcnt vmcnt(0)\n\t"
    "v_lshlrev_b32 v16, 16, v20\n\t"             // acc_i = pre_i
    "v_and_b32 v17, 0xffff0000, v20\n\t"         // acc_f = pre_f
    "v_lshlrev_b32 v18, 16, v21\n\t"             // acc_g = pre_g
    "v_and_b32 v19, 0xffff0000, v21\n\t"         // acc_o = pre_o
    "global_load_dwordx2 v[20:21], v26, %[ib]\n\t"
    "v_add_u32 v26, %[dis], v26\n\t"
    // h chunk pipeline: R0->A, R1->B, then dot/issue alternating
    "ds_read_b128 v[0:3], v23\n\t"
    "ds_read_b128 v[4:7], v23 offset:16\n\t"
    "ds_read_b128 v[8:11], v23 offset:32\n\t"
    "ds_read_b128 v[12:15], v23 offset:48\n\t"
    "s_waitcnt lgkmcnt(2)\n\t"
    DOT4(32,84,136,188, 0) DOT4(33,85,137,189, 1) DOT4(34,86,138,190, 2) DOT4(35,87,139,191, 3)
    DOT4(36,88,140,192, 4) DOT4(37,89,141,193, 5) DOT4(38,90,142,194, 6) DOT4(39,91,143,195, 7)
    "ds_read_b128 v[0:3], v23 offset:64\n\t"
    "ds_read_b128 v[4:7], v23 offset:80\n\t"
    "s_waitcnt lgkmcnt(2)\n\t"
    DOT4(40,92,144,196, 8)  DOT4(41,93,145,197, 9)  DOT4(42,94,146,198, 10) DOT4(43,95,147,199, 11)
    DOT4(44,96,148,200, 12) DOT4(45,97,149,201, 13) DOT4(46,98,150,202, 14) DOT4(47,99,151,203, 15)
    "ds_read_b128 v[8:11], v23 offset:96\n\t"
    "ds_read_b128 v[12:15], v23 offset:112\n\t"
    "s_waitcnt lgkmcnt(2)\n\t"
    DOT4(48,100,152,204, 0) DOT4(49,101,153,205, 1) DOT4(50,102,154,206, 2) DOT4(51,103,155,207, 3)
    DOT4(52,104,156,208, 4) DOT4(53,105,157,209, 5) DOT4(54,106,158,210, 6) DOT4(55,107,159,211, 7)
    "ds_read_b128 v[0:3], v23 offset:128\n\t"
    "ds_read_b128 v[4:7], v23 offset:144\n\t"
    "s_waitcnt lgkmcnt(2)\n\t"
    DOT4(56,108,160,212, 8)  DOT4(57,109,161,213, 9)  DOT4(58,110,162,214, 10) DOT4(59,111,163,215, 11)
    DOT4(60,112,164,216, 12) DOT4(61,113,165,217, 13) DOT4(62,114,166,218, 14) DOT4(63,115,167,219, 15)
    "ds_read_b128 v[8:11], v23 offset:160\n\t"
    "ds_read_b128 v[12:15], v23 offset:176\n\t"
    "s_waitcnt lgkmcnt(2)\n\t"
    DOT4(64,116,168,220, 0) DOT4(65,117,169,221, 1) DOT4(66,118,170,222, 2) DOT4(67,119,171,223, 3)
    DOT4(68,120,172,224, 4) DOT4(69,121,173,225, 5) DOT4(70,122,174,226, 6) DOT4(71,123,175,227, 7)
    "ds_read_b128 v[0:3], v23 offset:192\n\t"
    "s_waitcnt lgkmcnt(1)\n\t"
    DOT4(72,124,176,228, 8)  DOT4(73,125,177,229, 9)  DOT4(74,126,178,230, 10) DOT4(75,127,179,231, 11)
    DOT4(76,128,180,232, 12) DOT4(77,129,181,233, 13) DOT4(78,130,182,234, 14) DOT4(79,131,183,235, 15)
    "s_waitcnt lgkmcnt(0)\n\t"
    DOT4(80,132,184,236, 0) DOT4(81,133,185,237, 1) DOT4(82,134,186,238, 2) DOT4(83,135,187,239, 3)
    // activations (identical constants/order to r8/r9 -- passed)
    "v_mul_f32 v27, 0xbfb8aa3b, v17\n\t"
    "v_mul_f32 v28, 0xbfb8aa3b, v16\n\t"
    "v_mul_f32 v29, 0x4038aa3b, v18\n\t"
    "v_exp_f32 v27, v27\n\t"
    "v_exp_f32 v28, v28\n\t"
    "v_exp_f32 v29, v29\n\t"
    "v_add_f32 v27, 1.0, v27\n\t"
    "v_add_f32 v28, 1.0, v28\n\t"
    "v_add_f32 v29, 1.0, v29\n\t"
    "v_rcp_f32 v27, v27\n\t"                     // sf
    "v_rcp_f32 v28, v28\n\t"                     // si
    "v_rcp_f32 v29, v29\n\t"
    "v_mov_b32 v31, 1.0\n\t"
    "v_fmac_f32 v31, -2.0, v29\n\t"              // tg
    "v_mul_f32 v28, v28, v31\n\t"                // si*tg
    "v_fmac_f32 v28, v27, v30\n\t"               // + sf*c
    "v_mov_b32 v30, v28\n\t"                     // c
    "v_mul_f32 v27, 0x4038aa3b, v30\n\t"
    "v_mul_f32 v29, 0xbfb8aa3b, v19\n\t"
    "v_exp_f32 v27, v27\n\t"
    "v_exp_f32 v29, v29\n\t"
    "v_add_f32 v27, 1.0, v27\n\t"
    "v_add_f32 v29, 1.0, v29\n\t"
    "v_rcp_f32 v27, v27\n\t"
    "v_rcp_f32 v29, v29\n\t"                     // so
    "v_mov_b32 v31, 1.0\n\t"
    "v_fmac_f32 v31, -2.0, v27\n\t"              // tc
    "v_mul_f32 v28, v29, v31\n\t"                // h
    "v_cvt_pk_bf16_f32 v29, v28, v28\n\t"        // bf16 for hbt
    "v_cvt_f16_f32 v27, v28\n\t"                 // f16 for LDS h
    // stores (u<100 lanes only)
    "s_mov_b64 exec, %[se]\n\t"
    "ds_write_b16 v24, v27\n\t"
    "global_store_short v25, v29, %[hb]\n\t"
    "s_mov_b64 exec, -1\n\t"
    "v_add_u32 v25, %[dhs], v25\n\t"
    "v_xor_b32 v23, 0x100, v23\n\t"
    "v_xor_b32 v24, 0x100, v24\n\t"
    "s_waitcnt lgkmcnt(0)\n\t"
    "s_barrier\n\t"
    "s_sub_u32 s20, s20, 1\n\t"
    "s_cmp_lg_u32 s20, 0\n\t"
    "s_cbranch_scc1 LSTM_T%=\n\t"
    :
    : [sw]"s"(sw), [swb]"s"(swb),
      [sio]"s"(sio), [sho]"s"(sho), [sra]"s"(sra), [sha]"s"(sha),
      [wb]"s"(whhU), [ib]"s"(inp), [hb]"s"(hbt),
      [dis]"s"(dIb), [dhs]"s"(dHb), [se]"s"(se)
    : "memory","scc","s20",
      "v0","v1","v2","v3","v4","v5","v6","v7","v8","v9",
      "v10","v11","v12","v13","v14","v15","v16","v17","v18","v19",
      "v20","v21","v22","v23","v24","v25","v26","v27","v28","v29",
      "v30","v31","v32","v33","v34","v35","v36","v37","v38","v39",
      "v40","v41","v42","v43","v44","v45","v46","v47","v48","v49",
      "v50","v51","v52","v53","v54","v55","v56","v57","v58","v59",
      "v60","v61","v62","v63","v64","v65","v66","v67","v68","v69",
      "v70","v71","v72","v73","v74","v75","v76","v77","v78","v79",
      "v80","v81","v82","v83","v84","v85","v86","v87","v88","v89",
      "v90","v91","v92","v93","v94","v95","v96","v97","v98","v99",
      "v100","v101","v102","v103","v104","v105","v106","v107","v108","v109",
      "v110","v111","v112","v113","v114","v115","v116","v117","v118","v119",
      "v120","v121","v122","v123","v124","v125","v126","v127","v128","v129",
      "v130","v131","v132","v133","v134","v135","v136","v137","v138","v139",
      "v140","v141","v142","v143","v144","v145","v146","v147","v148","v149",
      "v150","v151","v152","v153","v154","v155","v156","v157","v158","v159",
      "v160","v161","v162","v163","v164","v165","v166","v167","v168","v169",
      "v170","v171","v172","v173","v174","v175","v176","v177","v178","v179",
      "v180","v181","v182","v183","v184","v185","v186","v187","v188","v189",
      "v190","v191","v192","v193","v194","v195","v196","v197","v198","v199",
      "v200","v201","v202","v203","v204","v205","v206","v207","v208","v209",
      "v210","v211","v212","v213","v214","v215","v216","v217","v218","v219",
      "v220","v221","v222","v223","v224","v225","v226","v227","v228","v229",
      "v230","v231","v232","v233","v234","v235","v236","v237","v238","v239"
  );
}

// ---------- MLP: gathered bf16 MFMA GEMM + tanh + W2 + softmax fused ----------
__global__ __launch_bounds__(512) void mlp_kernel(const u16* __restrict__ hbt,
    const u16* __restrict__ w1b, const int* __restrict__ paths,
    const float* __restrict__ b1, const float* __restrict__ W2,
    const float* __restrict__ b2, float* __restrict__ out)
{
  __shared__ __align__(16) u16 As[128*40];
  __shared__ __align__(16) u16 Bs[320*40];
  const int m0 = blockIdx.x*128;
  const int tid = threadIdx.x;
  const int arow = tid >> 2, ac8 = tid & 3;
  const int am = m0 + arow;
  const int ab = am / 255;
  const int w = tid >> 6, lane = tid & 63, col = lane & 15, quad = lane >> 4;
  f32x4 acc[20];
  #pragma unroll
  for (int nt=0;nt<20;nt++) acc[nt] = (f32x4){0.f,0.f,0.f,0.f};
  for (int kc=0;kc<21;kc++){
    __syncthreads();
    for (int f = tid; f < 1280; f += 512){
      int br = f >> 2, bc = f & 3;
      *(uint4*)&Bs[br*40 + bc*8] = *(const uint4*)&w1b[br*672 + kc*32 + bc*8];
    }
    int seg = (kc >= 14) ? 2 : (kc >= 7 ? 1 : 0);
    int ko = kc - seg*7;
    int it = paths[am*3 + seg];
    uint4 v = make_uint4(0u,0u,0u,0u);
    if (it >= 0){
      int t = it > 127 ? 127 : it;
      v = *(const uint4*)&hbt[(ab*128 + t)*224 + ko*32 + ac8*8];
    }
    *(uint4*)&As[arow*40 + ac8*8] = v;
    __syncthreads();
    short8 af = *(const short8*)&As[(w*16+col)*40 + quad*8];
    #pragma unroll
    for (int nt=0;nt<20;nt++){
      short8 bfrag = *(const short8*)&Bs[(nt*16+col)*40 + quad*8];
      acc[nt] = __builtin_amdgcn_mfma_f32_16x16x32_bf16(af, bfrag, acc[nt], 0, 0, 0);
    }
  }
  float pz[4][3];
  #pragma unroll
  for (int r=0;r<4;r++){ pz[r][0]=0.f; pz[r][1]=0.f; pz[r][2]=0.f; }
  #pragma unroll
  for (int nt=0;nt<20;nt++){
    int n = nt*16 + col;
    if (n < 300){
      float bb = b1[n];
      float w20 = W2[n*3+0], w21 = W2[n*3+1], w22 = W2[n*3+2];
      #pragma unroll
      for (int r=0;r<4;r++){
        float hdn = tanh_f(acc[nt][r] + bb);
        pz[r][0] = fmaf(hdn, w20, pz[r][0]);
        pz[r][1] = fmaf(hdn, w21, pz[r][1]);
        pz[r][2] = fmaf(hdn, w22, pz[r][2]);
      }
    }
  }
  #pragma unroll
  for (int off=1; off<16; off<<=1){
    #pragma unroll
    for (int r=0;r<4;r++){
      pz[r][0] += __shfl_xor(pz[r][0], off, 64);
      pz[r][1] += __shfl_xor(pz[r][1], off, 64);
      pz[r][2] += __shfl_xor(pz[r][2], off, 64);
    }
  }
  float c0 = b2[0], c1 = b2[1], c2 = b2[2];
  #pragma unroll
  for (int r=0;r<4;r++){
    float z0 = pz[r][0]+c0, z1 = pz[r][1]+c1, z2 = pz[r][2]+c2;
    float mx = fmaxf(z0, fmaxf(z1, z2));
    float e0 = __expf(z0-mx), e1 = __expf(z1-mx), e2 = __expf(z2-mx);
    float inv = 1.0f/(e0+e1+e2);
    if (col < 3){
      float pv = (col==0 ? e0 : (col==1 ? e1 : e2)) * inv;
      out[(m0 + w*16 + quad*4 + r)*3 + col] = pv;
    }
  }
}

// ---------- launch ----------
extern "C" void kernel_launch(void* const* d_in, const int* in_sizes, int n_in,
                              void* d_out, int out_size, void* d_ws, size_t ws_size,
                              hipStream_t stream)
{
  const int*   x     = (const int*)  d_in[0];
  const int*   paths = (const int*)  d_in[1];
  const float* emb   = (const float*)d_in[2];
  const float* Wih_f = (const float*)d_in[3];
  const float* Whh_f = (const float*)d_in[4];
  const float* bih_f = (const float*)d_in[5];
  const float* bhh_f = (const float*)d_in[6];
  const float* Wih_b = (const float*)d_in[7];
  const float* Whh_b = (const float*)d_in[8];
  const float* bih_b = (const float*)d_in[9];
  const float* bhh_b = (const float*)d_in[10];
  const float* W1    = (const float*)d_in[11];
  const float* b1    = (const float*)d_in[12];
  const float* W2    = (const float*)d_in[13];
  const float* b2    = (const float*)d_in[14];
  float* out = (float*)d_out;

  char* ws = (char*)d_ws;
  u16*   xe    = (u16*)  (ws + 0);          //  8,388,608 B
  u16*   wc    = (u16*)  (ws + 8388608);    //    212,992 B
  float* biasC = (float*)(ws + 8601600);    //      3,200 B
  u16*   whhU  = (u16*)  (ws + 8604800);    //    212,992 B
  u16*   w1b   = (u16*)  (ws + 8817792);    //    430,080 B
  u16*   inp   = (u16*)  (ws + 9247872);    // 52,428,800 B
  u16*   hbt   = (u16*)  (ws + 61676672);   // 14,680,064 B  (total 76,356,736)

  const int prep_total = 32768*128 + 832*128 + 800 + 106496 + 672*320 + 32768*24;
  prep_kernel<<<(prep_total + 255)/256, 256, 0, stream>>>(
      x, emb, Wih_f, Whh_f, bih_f, bhh_f, Wih_b, Whh_b, bih_b, bhh_b, W1,
      xe, wc, biasC, whhU, w1b, hbt);
  gemm1_kernel<<<dim3(512, 13), 256, 0, stream>>>(xe, wc, biasC, inp);
  lstm_kernel<<<512, 128, 0, stream>>>(inp, whhU, hbt);
  mlp_kernel<<<510, 512, 0, stream>>>(hbt, w1b, paths, b1, W2, b2, out);
}